// Round 1
// baseline (764.021 us; speedup 1.0000x reference)
//
#include <hip/hip_runtime.h>
#include <hip/hip_bf16.h>
#include <stdint.h>

#define NN 8192
#define DIM 256
#define NSPEC 32
#define ETA 0.5f
#define COEFF 0.125f      // D/(N*EPS^2) = 256/(8192*0.25)
#define LNEPS 1e-5f

typedef __attribute__((ext_vector_type(8))) short bf16x8;
typedef __attribute__((ext_vector_type(4))) float f32x4;

__device__ __forceinline__ unsigned short bf2u(__hip_bfloat16 b) {
    union { __hip_bfloat16 b; unsigned short u; } c; c.b = b; return c.u;
}
__device__ __forceinline__ __hip_bfloat16 u2bf(unsigned short u) {
    union { __hip_bfloat16 b; unsigned short u; } c; c.u = u; return c.b;
}

__device__ __forceinline__ void async16(const void* g, void* l) {
    __builtin_amdgcn_global_load_lds(
        (const __attribute__((address_space(1))) void*)g,
        (__attribute__((address_space(3))) void*)l, 16, 0, 0);
}

// ---------------- cast A (f32 -> bf16), 64M elements ----------------
__global__ void cast_A(const float4* __restrict__ src, ushort4* __restrict__ dst, int n4) {
    int i = blockIdx.x * 256 + threadIdx.x;
    int stride = gridDim.x * 256;
    for (int j = i; j < n4; j += stride) {
        float4 v = src[j];
        ushort4 o;
        o.x = bf2u(__float2bfloat16(v.x));
        o.y = bf2u(__float2bfloat16(v.y));
        o.z = bf2u(__float2bfloat16(v.z));
        o.w = bf2u(__float2bfloat16(v.w));
        dst[j] = o;
    }
}

// ---------------- cast + transpose H: f32 (8192x256) -> bf16 m-major + bf16 d-major ----------------
__global__ void cast_trans(const float* __restrict__ X, __hip_bfloat16* __restrict__ Xbf,
                           __hip_bfloat16* __restrict__ XT) {
    __shared__ unsigned short tile[64 * 66];
    int r0 = blockIdx.x * 64, c0 = blockIdx.y * 64;
    int t = threadIdx.x;
    for (int i = 0; i < 16; ++i) {
        int idx = i * 256 + t;
        int r = idx >> 6, c = idx & 63;
        float v = X[(long)(r0 + r) * DIM + c0 + c];
        __hip_bfloat16 b = __float2bfloat16(v);
        Xbf[(long)(r0 + r) * DIM + c0 + c] = b;
        tile[r * 66 + c] = bf2u(b);
    }
    __syncthreads();
    for (int i = 0; i < 16; ++i) {
        int idx = i * 256 + t;
        int c = idx >> 6, r = idx & 63;
        XT[(long)(c0 + c) * NN + r0 + r] = u2bf(tile[r * 66 + c]);
    }
}

// ---------------- transpose bf16 (8192x256) -> (256x8192) ----------------
__global__ void trans_bf16(const __hip_bfloat16* __restrict__ X, __hip_bfloat16* __restrict__ XT) {
    __shared__ unsigned short tile[64 * 66];
    int r0 = blockIdx.x * 64, c0 = blockIdx.y * 64;
    int t = threadIdx.x;
    for (int i = 0; i < 16; ++i) {
        int idx = i * 256 + t;
        int r = idx >> 6, c = idx & 63;
        tile[r * 66 + c] = bf2u(X[(long)(r0 + r) * DIM + c0 + c]);
    }
    __syncthreads();
    for (int i = 0; i < 16; ++i) {
        int idx = i * 256 + t;
        int c = idx >> 6, r = idx & 63;
        XT[(long)(c0 + c) * NN + r0 + r] = u2bf(tile[r * 66 + c]);
    }
}

// ---------------- GEMM: C(8192x256 bf16) = A(8192x8192 bf16) @ BT^T (BT is 256x8192 bf16) -------
// BM=128 BN=64 BK=64, 256 threads (4 waves, 2x2), 16x16x32 bf16 MFMA, XOR-swizzled LDS.
#define BM 128
#define BN 64
#define BK 64

__launch_bounds__(256, 1)
__global__ void gemm_hop(const __hip_bfloat16* __restrict__ A,
                         const __hip_bfloat16* __restrict__ BT,
                         __hip_bfloat16* __restrict__ C) {
    __shared__ __align__(16) __hip_bfloat16 As[BM * BK];
    __shared__ __align__(16) __hip_bfloat16 Bs[BN * BK];
    const int t = threadIdx.x;
    const int w = t >> 6, l = t & 63;
    const int wm = w & 1, wn = w >> 1;
    const long gm0 = (long)blockIdx.x * BM;
    const long gn0 = (long)blockIdx.y * BN;

    const int lr = l >> 3;                 // row within 8-row chunk
    const int lg = l & 7;                  // physical 16B col-group
    const int glog = lg ^ (lr & 7);        // logical col-group to fetch (XOR swizzle)

    f32x4 acc[4][2];
#pragma unroll
    for (int mt = 0; mt < 4; ++mt)
#pragma unroll
        for (int nt = 0; nt < 2; ++nt)
            acc[mt][nt] = (f32x4){0.f, 0.f, 0.f, 0.f};

    const int rowq = l & 15;   // MFMA row/col within 16
    const int kq = l >> 4;     // quad -> k-group

    for (int k0 = 0; k0 < NN; k0 += BK) {
        // stage A: 4 wave-calls x (8 rows x 128B)
#pragma unroll
        for (int c = 0; c < 4; ++c) {
            int r = c * 32 + w * 8 + lr;
            async16(A + (gm0 + r) * (long)NN + k0 + glog * 8,
                    &As[(c * 32 + w * 8) * BK]);
        }
        // stage B: 2 wave-calls
#pragma unroll
        for (int c = 0; c < 2; ++c) {
            int r = c * 32 + w * 8 + lr;
            async16(BT + (gn0 + r) * (long)NN + k0 + glog * 8,
                    &Bs[(c * 32 + w * 8) * BK]);
        }
        __syncthreads();

        bf16x8 af[4][2], bfr[2][2];
#pragma unroll
        for (int ks = 0; ks < 2; ++ks) {
            int kg = kq + ks * 4;
#pragma unroll
            for (int mt = 0; mt < 4; ++mt) {
                int m = wm * 64 + mt * 16 + rowq;
                af[mt][ks] = *(const bf16x8*)&As[m * BK + ((kg ^ (m & 7)) << 3)];
            }
#pragma unroll
            for (int nt = 0; nt < 2; ++nt) {
                int n = wn * 32 + nt * 16 + rowq;
                bfr[nt][ks] = *(const bf16x8*)&Bs[n * BK + ((kg ^ (n & 7)) << 3)];
            }
        }
#pragma unroll
        for (int ks = 0; ks < 2; ++ks)
#pragma unroll
            for (int mt = 0; mt < 4; ++mt)
#pragma unroll
                for (int nt = 0; nt < 2; ++nt)
                    acc[mt][nt] = __builtin_amdgcn_mfma_f32_16x16x32_bf16(
                        af[mt][ks], bfr[nt][ks], acc[mt][nt], 0, 0, 0);
        __syncthreads();
    }

    // epilogue: C/D layout col=lane&15, row=(lane>>4)*4+reg
#pragma unroll
    for (int mt = 0; mt < 4; ++mt)
#pragma unroll
        for (int nt = 0; nt < 2; ++nt)
#pragma unroll
            for (int r = 0; r < 4; ++r) {
                long m = gm0 + wm * 64 + mt * 16 + (l >> 4) * 4 + r;
                long n = gn0 + wn * 32 + nt * 16 + (l & 15);
                C[m * DIM + n] = __float2bfloat16(acc[mt][nt][r]);
            }
}

// ---------------- Phi[k,s,d] = sum_n V[n,s] * hop_k[n,d]  (atomic split over n) ----------------
// grid (16 chunks, 4 k, 4 s-groups), 256 threads; thread owns d=t, 8 s values.
__global__ void phi_kernel(const float* __restrict__ V,
                           const __hip_bfloat16* __restrict__ X0,
                           const __hip_bfloat16* __restrict__ X1,
                           const __hip_bfloat16* __restrict__ X2,
                           const __hip_bfloat16* __restrict__ X3,
                           float* __restrict__ Phi) {
    __shared__ float ldsV[64 * 8];
    int t = threadIdx.x;
    int n0 = blockIdx.x * 512;
    int k = blockIdx.y;
    int s0 = blockIdx.z * 8;
    const __hip_bfloat16* X = (k == 0) ? X0 : (k == 1) ? X1 : (k == 2) ? X2 : X3;
    float acc[8] = {0.f, 0.f, 0.f, 0.f, 0.f, 0.f, 0.f, 0.f};
    for (int tile = 0; tile < 8; ++tile) {
        int nb = n0 + tile * 64;
#pragma unroll
        for (int i = 0; i < 2; ++i) {
            int idx = i * 256 + t;
            int r = idx >> 3, c = idx & 7;
            ldsV[idx] = V[(long)(nb + r) * NSPEC + s0 + c];
        }
        __syncthreads();
        for (int nn = 0; nn < 64; ++nn) {
            float x = __bfloat162float(X[(long)(nb + nn) * DIM + t]);
#pragma unroll
            for (int s = 0; s < 8; ++s) acc[s] += ldsV[nn * 8 + s] * x;
        }
        __syncthreads();
    }
#pragma unroll
    for (int s = 0; s < 8; ++s)
        atomicAdd(&Phi[(k * NSPEC + s0 + s) * DIM + t], acc[s]);
}

// ---------------- Tc[s,d] = spec_w*sum_k hw*q - lap*eig*sum_k hw*phi; also writes tail outputs --
__global__ void tc_kernel(const float* __restrict__ Phi,
                          const float* __restrict__ eigvals,
                          const float* __restrict__ spec_logits,
                          const float* __restrict__ lap_logits,
                          const float* __restrict__ hop_weights,
                          float* __restrict__ Tc,
                          float* __restrict__ out_tail) {
    int s = blockIdx.x, t = threadIdx.x;
    // hop softmax (4)
    float hw0 = hop_weights[0], hw1 = hop_weights[1], hw2 = hop_weights[2], hw3 = hop_weights[3];
    float hm = fmaxf(fmaxf(hw0, hw1), fmaxf(hw2, hw3));
    hw0 = expf(hw0 - hm); hw1 = expf(hw1 - hm); hw2 = expf(hw2 - hm); hw3 = expf(hw3 - hm);
    float hs = hw0 + hw1 + hw2 + hw3;
    hw0 /= hs; hw1 /= hs; hw2 /= hs; hw3 /= hs;
    float hw[4] = {hw0, hw1, hw2, hw3};
    // spec softmax (32), two passes, no reg array
    float sm = -1e30f;
    for (int j = 0; j < NSPEC; ++j) sm = fmaxf(sm, spec_logits[j]);
    float ssum = 0.f;
    for (int j = 0; j < NSPEC; ++j) ssum += expf(spec_logits[j] - sm);
    float spec_w_s = expf(spec_logits[s] - sm) / ssum;
    float lp = lap_logits[s];
    float lap = (lp > 20.f) ? lp : log1pf(expf(lp));
    float le = lap * eigvals[s];

    __shared__ float red[4];
    float accR = 0.f, accL = 0.f;
    for (int k = 0; k < 4; ++k) {
        float phi = Phi[(k * NSPEC + s) * DIM + t];
        float v = phi * phi;
        for (int off = 32; off; off >>= 1) v += __shfl_xor(v, off);
        if ((t & 63) == 0) red[t >> 6] = v;
        __syncthreads();
        float ssq = red[0] + red[1] + red[2] + red[3];
        __syncthreads();
        float q = COEFF * phi / (1.f + COEFF * ssq);
        accR += hw[k] * q;
        accL += hw[k] * phi;
    }
    Tc[s * DIM + t] = spec_w_s * accR - le * accL;
    if (s == 0) {
        if (t < 4) out_tail[t] = hw[t];
        if (t < NSPEC) out_tail[4 + t] = expf(spec_logits[t] - sm) / ssum;
    }
}

// ---------------- final: G=V@Tc, H_half=H+ETA*G, soft-threshold, LayerNorm ----------------
__launch_bounds__(256)
__global__ void final_kernel(const float* __restrict__ H, const float* __restrict__ V,
                             const float* __restrict__ Tc, const float* __restrict__ thr,
                             const float* __restrict__ gamma, const float* __restrict__ beta,
                             float* __restrict__ out) {
    __shared__ float tc[NSPEC * DIM];   // 32 KB
    int t = threadIdx.x;
    {
        const float4* s4 = (const float4*)Tc;
        float4* d4 = (float4*)tc;
        for (int i = 0; i < 8; ++i) d4[i * 256 + t] = s4[i * 256 + t];
    }
    __syncthreads();
    int w = t >> 6, l = t & 63;
    long row = (long)blockIdx.x * 4 + w;
    int d0 = l * 4;
    const float* vrow = V + row * NSPEC;
    float4 G = {0.f, 0.f, 0.f, 0.f};
#pragma unroll 8
    for (int s = 0; s < NSPEC; ++s) {
        float vs = vrow[s];
        float4 c4 = *(const float4*)&tc[s * DIM + d0];
        G.x += vs * c4.x; G.y += vs * c4.y; G.z += vs * c4.z; G.w += vs * c4.w;
    }
    float4 h = *(const float4*)&H[row * DIM + d0];
    float4 th = *(const float4*)&thr[d0];
    float y[4];
    y[0] = h.x + ETA * G.x; y[1] = h.y + ETA * G.y;
    y[2] = h.z + ETA * G.z; y[3] = h.w + ETA * G.w;
    float tv[4] = {th.x, th.y, th.z, th.w};
    float s1 = 0.f, s2 = 0.f;
#pragma unroll
    for (int j = 0; j < 4; ++j) {
        float a = fabsf(y[j]) - tv[j];
        y[j] = (a > 0.f) ? copysignf(a, y[j]) : 0.f;
        s1 += y[j];
        s2 += y[j] * y[j];
    }
    for (int off = 32; off; off >>= 1) { s1 += __shfl_xor(s1, off); s2 += __shfl_xor(s2, off); }
    float mean = s1 * (1.f / DIM);
    float var = s2 * (1.f / DIM) - mean * mean;
    float inv = rsqrtf(var + LNEPS);
    float4 g4 = *(const float4*)&gamma[d0];
    float4 b4 = *(const float4*)&beta[d0];
    float4 o;
    o.x = (y[0] - mean) * inv * g4.x + b4.x;
    o.y = (y[1] - mean) * inv * g4.y + b4.y;
    o.z = (y[2] - mean) * inv * g4.z + b4.z;
    o.w = (y[3] - mean) * inv * g4.w + b4.w;
    *(float4*)&out[row * DIM + d0] = o;
}

extern "C" void kernel_launch(void* const* d_in, const int* in_sizes, int n_in,
                              void* d_out, int out_size, void* d_ws, size_t ws_size,
                              hipStream_t stream) {
    const float* H = (const float*)d_in[0];
    const float* A = (const float*)d_in[1];
    const float* V = (const float*)d_in[2];
    const float* eigvals = (const float*)d_in[3];
    const float* spec_logits = (const float*)d_in[4];
    const float* lap_logits = (const float*)d_in[5];
    const float* hop_weights = (const float*)d_in[6];
    const float* threshold = (const float*)d_in[7];
    const float* ln_gamma = (const float*)d_in[8];
    const float* ln_beta = (const float*)d_in[9];

    char* ws = (char*)d_ws;
    __hip_bfloat16* Abf  = (__hip_bfloat16*)ws;                      // 134217728 B
    __hip_bfloat16* H0bf = (__hip_bfloat16*)(ws + 134217728);        // 4 MB m-major
    __hip_bfloat16* H0T  = (__hip_bfloat16*)(ws + 138412032);        // 4 MB d-major
    __hip_bfloat16* C1   = (__hip_bfloat16*)(ws + 142606336);
    __hip_bfloat16* C1T  = (__hip_bfloat16*)(ws + 146800640);
    __hip_bfloat16* C2   = (__hip_bfloat16*)(ws + 150994944);
    __hip_bfloat16* C2T  = (__hip_bfloat16*)(ws + 155189248);
    __hip_bfloat16* C3   = (__hip_bfloat16*)(ws + 159383552);
    float* Phi = (float*)(ws + 163577856);                           // 128 KB
    float* Tc  = (float*)(ws + 163708928);                           // 32 KB
    float* out = (float*)d_out;

    hipMemsetAsync(Phi, 0, 4 * NSPEC * DIM * sizeof(float), stream);
    cast_A<<<4096, 256, 0, stream>>>((const float4*)A, (ushort4*)Abf, NN * NN / 4);
    cast_trans<<<dim3(128, 4), 256, 0, stream>>>(H, H0bf, H0T);
    gemm_hop<<<dim3(64, 4), 256, 0, stream>>>(Abf, H0T, C1);
    trans_bf16<<<dim3(128, 4), 256, 0, stream>>>(C1, C1T);
    gemm_hop<<<dim3(64, 4), 256, 0, stream>>>(Abf, C1T, C2);
    trans_bf16<<<dim3(128, 4), 256, 0, stream>>>(C2, C2T);
    gemm_hop<<<dim3(64, 4), 256, 0, stream>>>(Abf, C2T, C3);
    phi_kernel<<<dim3(16, 4, 4), 256, 0, stream>>>(V, H0bf, C1, C2, C3, Phi);
    tc_kernel<<<NSPEC, 256, 0, stream>>>(Phi, eigvals, spec_logits, lap_logits, hop_weights,
                                         Tc, out + (long)NN * DIM);
    final_kernel<<<2048, 256, 0, stream>>>(H, V, Tc, threshold, ln_gamma, ln_beta, out);
}

// Round 2
// 681.516 us; speedup vs baseline: 1.1211x; 1.1211x over previous
//
#include <hip/hip_runtime.h>
#include <hip/hip_bf16.h>
#include <stdint.h>

#define NN 8192
#define DIM 256
#define NSPEC 32
#define ETA 0.5f
#define COEFF 0.125f      // D/(N*EPS^2) = 256/(8192*0.25)
#define LNEPS 1e-5f

typedef __attribute__((ext_vector_type(8))) short bf16x8;
typedef __attribute__((ext_vector_type(4))) float f32x4;

__device__ __forceinline__ unsigned short bf2u(__hip_bfloat16 b) {
    union { __hip_bfloat16 b; unsigned short u; } c; c.b = b; return c.u;
}
__device__ __forceinline__ __hip_bfloat16 u2bf(unsigned short u) {
    union { __hip_bfloat16 b; unsigned short u; } c; c.u = u; return c.b;
}
__device__ __forceinline__ float bfbits2f(unsigned short u) {
    union { unsigned int i; float f; } c; c.i = ((unsigned int)u) << 16; return c.f;
}

__device__ __forceinline__ void async16(const void* g, void* l) {
    __builtin_amdgcn_global_load_lds(
        (const __attribute__((address_space(1))) void*)g,
        (__attribute__((address_space(3))) void*)l, 16, 0, 0);
}

// ---------------- cast A (f32 -> bf16), 64M elements ----------------
__global__ void cast_A(const float4* __restrict__ src, ushort4* __restrict__ dst, int n4) {
    int i = blockIdx.x * 256 + threadIdx.x;
    int stride = gridDim.x * 256;
    for (int j = i; j < n4; j += stride) {
        float4 v = src[j];
        ushort4 o;
        o.x = bf2u(__float2bfloat16(v.x));
        o.y = bf2u(__float2bfloat16(v.y));
        o.z = bf2u(__float2bfloat16(v.z));
        o.w = bf2u(__float2bfloat16(v.w));
        dst[j] = o;
    }
}

// ---------------- cast + transpose H: f32 (8192x256) -> bf16 m-major + bf16 d-major ----------------
__global__ void cast_trans(const float* __restrict__ X, __hip_bfloat16* __restrict__ Xbf,
                           __hip_bfloat16* __restrict__ XT) {
    __shared__ unsigned short tile[64 * 66];
    int r0 = blockIdx.x * 64, c0 = blockIdx.y * 64;
    int t = threadIdx.x;
    for (int i = 0; i < 16; ++i) {
        int idx = i * 256 + t;
        int r = idx >> 6, c = idx & 63;
        float v = X[(long)(r0 + r) * DIM + c0 + c];
        __hip_bfloat16 b = __float2bfloat16(v);
        Xbf[(long)(r0 + r) * DIM + c0 + c] = b;
        tile[r * 66 + c] = bf2u(b);
    }
    __syncthreads();
    for (int i = 0; i < 16; ++i) {
        int idx = i * 256 + t;
        int c = idx >> 6, r = idx & 63;
        XT[(long)(c0 + c) * NN + r0 + r] = u2bf(tile[r * 66 + c]);
    }
}

// ---------------- split-K GEMM ----------------------------------------------------------------
// C(8192x256) = A(8192x8192 bf16) @ BT^T (BT is 256x8192 bf16), f32 partials per k-split.
// BM=128 BN=128 BK=64, split-K=4 (Kc=2048). 256 threads = 4 waves (2x2), wave-tile 64x64.
// Double-buffered LDS (2 x 32 KB), one barrier per K-iter, global_load_lds width-16 staging,
// XOR-swizzled LDS. Grid 64x2x4 = 512 blocks = 2 blocks/CU (64 KB LDS), 8 waves/CU.
#define BM 128
#define BN 128
#define BK 64
#define KSPLIT 4
#define KC (NN / KSPLIT)
#define KITERS (KC / BK)

__launch_bounds__(256, 2)
__global__ void gemm_splitk(const __hip_bfloat16* __restrict__ A,
                            const __hip_bfloat16* __restrict__ BT,
                            float* __restrict__ P) {
    __shared__ __align__(16) __hip_bfloat16 As[2][BM * BK];
    __shared__ __align__(16) __hip_bfloat16 Bs[2][BN * BK];
    const int t = threadIdx.x;
    const int w = t >> 6, l = t & 63;
    const int wm = w & 1, wn = w >> 1;
    const long gm0 = (long)blockIdx.x * BM;
    const long gn0 = (long)blockIdx.y * BN;
    const long kbase = (long)blockIdx.z * KC;

    const int lr = l >> 3;                 // 0..7: row within 8-row chunk of one async16 call
    const int lg = l & 7;                  // physical 16B col-group
    const int glog = lg ^ lr;              // logical col-group to fetch (XOR swizzle)

    auto stage = [&](int buf, long kpos) {
#pragma unroll
        for (int c = 0; c < 4; ++c) {
            int rb = w * 32 + c * 8;
            async16(A + (gm0 + rb + lr) * (long)NN + kpos + glog * 8, &As[buf][rb * BK]);
        }
#pragma unroll
        for (int c = 0; c < 4; ++c) {
            int rb = w * 32 + c * 8;
            async16(BT + (gn0 + rb + lr) * (long)NN + kpos + glog * 8, &Bs[buf][rb * BK]);
        }
    };

    f32x4 acc[4][4];
#pragma unroll
    for (int mt = 0; mt < 4; ++mt)
#pragma unroll
        for (int nt = 0; nt < 4; ++nt)
            acc[mt][nt] = (f32x4){0.f, 0.f, 0.f, 0.f};

    const int rowq = l & 15;   // MFMA row/col within 16
    const int kq = l >> 4;     // quad -> k-group

    stage(0, kbase);
    for (int kt = 0; kt < KITERS; ++kt) {
        __syncthreads();                       // drains vmcnt: buf[cur] ready
        const int cur = kt & 1;
        if (kt + 1 < KITERS) stage(cur ^ 1, kbase + (long)(kt + 1) * BK);

#pragma unroll
        for (int ks = 0; ks < 2; ++ks) {
            const int kg = kq + ks * 4;
            bf16x8 af[4], bfr[4];
#pragma unroll
            for (int mt = 0; mt < 4; ++mt) {
                int m = wm * 64 + mt * 16 + rowq;
                af[mt] = *(const bf16x8*)&As[cur][m * BK + ((kg ^ (m & 7)) << 3)];
            }
#pragma unroll
            for (int nt = 0; nt < 4; ++nt) {
                int n = wn * 64 + nt * 16 + rowq;
                bfr[nt] = *(const bf16x8*)&Bs[cur][n * BK + ((kg ^ (n & 7)) << 3)];
            }
#pragma unroll
            for (int mt = 0; mt < 4; ++mt)
#pragma unroll
                for (int nt = 0; nt < 4; ++nt)
                    acc[mt][nt] = __builtin_amdgcn_mfma_f32_16x16x32_bf16(
                        af[mt], bfr[nt], acc[mt][nt], 0, 0, 0);
        }
    }

    // epilogue: C/D layout col=lane&15, row=(lane>>4)*4+reg  -> f32 partials, unique region per block
    float* Pz = P + (long)blockIdx.z * NN * DIM;
#pragma unroll
    for (int mt = 0; mt < 4; ++mt)
#pragma unroll
        for (int nt = 0; nt < 4; ++nt)
#pragma unroll
            for (int r = 0; r < 4; ++r) {
                long m = gm0 + wm * 64 + mt * 16 + (l >> 4) * 4 + r;
                long n = gn0 + wn * 64 + nt * 16 + (l & 15);
                Pz[m * DIM + n] = acc[mt][nt][r];
            }
}

// ---------------- reduce 4 k-split partials + cast bf16 + optional transpose -------------------
__global__ void reduce_ct(const float* __restrict__ P, __hip_bfloat16* __restrict__ Xbf,
                          __hip_bfloat16* __restrict__ XT, int writeT) {
    __shared__ unsigned short tile[64 * 66];
    int r0 = blockIdx.x * 64, c0 = blockIdx.y * 64;
    int t = threadIdx.x;
    const long S = (long)NN * DIM;
    for (int i = 0; i < 16; ++i) {
        int idx = i * 256 + t;
        int r = idx >> 6, c = idx & 63;
        long off = (long)(r0 + r) * DIM + c0 + c;
        float v = P[off] + P[S + off] + P[2 * S + off] + P[3 * S + off];
        __hip_bfloat16 b = __float2bfloat16(v);
        Xbf[off] = b;
        tile[r * 66 + c] = bf2u(b);
    }
    __syncthreads();
    if (writeT) {
        for (int i = 0; i < 16; ++i) {
            int idx = i * 256 + t;
            int c = idx >> 6, r = idx & 63;
            XT[(long)(c0 + c) * NN + r0 + r] = u2bf(tile[r * 66 + c]);
        }
    }
}

// ---------------- Phi[k,s,d] = sum_n V[n,s] * hop_k[n,d]  (atomic split over n) ----------------
// grid (64 n-chunks, 4 k), 256 threads. Thread: 8 spec (t>>6 group) x 4 d ((t&63)*4).
__global__ void phi_kernel(const float* __restrict__ V,
                           const __hip_bfloat16* __restrict__ X0,
                           const __hip_bfloat16* __restrict__ X1,
                           const __hip_bfloat16* __restrict__ X2,
                           const __hip_bfloat16* __restrict__ X3,
                           float* __restrict__ Phi) {
    __shared__ float ldsV[64 * NSPEC];   // 8 KB
    int t = threadIdx.x;
    int s0 = (t >> 6) * 8;
    int d0 = (t & 63) * 4;
    int n0 = blockIdx.x * 128;
    int k = blockIdx.y;
    const __hip_bfloat16* X = (k == 0) ? X0 : (k == 1) ? X1 : (k == 2) ? X2 : X3;
    float4 acc[8];
#pragma unroll
    for (int j = 0; j < 8; ++j) acc[j] = (float4){0.f, 0.f, 0.f, 0.f};

    for (int tile = 0; tile < 2; ++tile) {
        int nb = n0 + tile * 64;
#pragma unroll
        for (int i = 0; i < 8; ++i) {
            int idx = i * 256 + t;
            int r = idx >> 5, c = idx & 31;
            ldsV[idx] = V[(long)(nb + r) * NSPEC + c];
        }
        __syncthreads();
        for (int nn = 0; nn < 64; ++nn) {
            ushort4 xu = *(const ushort4*)&X[(long)(nb + nn) * DIM + d0];
            float x0 = bfbits2f(xu.x), x1 = bfbits2f(xu.y), x2 = bfbits2f(xu.z), x3 = bfbits2f(xu.w);
#pragma unroll
            for (int j = 0; j < 8; ++j) {
                float vs = ldsV[nn * NSPEC + s0 + j];
                acc[j].x += vs * x0; acc[j].y += vs * x1;
                acc[j].z += vs * x2; acc[j].w += vs * x3;
            }
        }
        __syncthreads();
    }
#pragma unroll
    for (int j = 0; j < 8; ++j) {
        float* ph = &Phi[((k * NSPEC) + s0 + j) * DIM + d0];
        atomicAdd(ph + 0, acc[j].x);
        atomicAdd(ph + 1, acc[j].y);
        atomicAdd(ph + 2, acc[j].z);
        atomicAdd(ph + 3, acc[j].w);
    }
}

// ---------------- Tc[s,d] = spec_w*sum_k hw*q - lap*eig*sum_k hw*phi; also writes tail outputs --
__global__ void tc_kernel(const float* __restrict__ Phi,
                          const float* __restrict__ eigvals,
                          const float* __restrict__ spec_logits,
                          const float* __restrict__ lap_logits,
                          const float* __restrict__ hop_weights,
                          float* __restrict__ Tc,
                          float* __restrict__ out_tail) {
    int s = blockIdx.x, t = threadIdx.x;
    float hw0 = hop_weights[0], hw1 = hop_weights[1], hw2 = hop_weights[2], hw3 = hop_weights[3];
    float hm = fmaxf(fmaxf(hw0, hw1), fmaxf(hw2, hw3));
    hw0 = expf(hw0 - hm); hw1 = expf(hw1 - hm); hw2 = expf(hw2 - hm); hw3 = expf(hw3 - hm);
    float hs = hw0 + hw1 + hw2 + hw3;
    hw0 /= hs; hw1 /= hs; hw2 /= hs; hw3 /= hs;
    float hw[4] = {hw0, hw1, hw2, hw3};
    float sm = -1e30f;
    for (int j = 0; j < NSPEC; ++j) sm = fmaxf(sm, spec_logits[j]);
    float ssum = 0.f;
    for (int j = 0; j < NSPEC; ++j) ssum += expf(spec_logits[j] - sm);
    float spec_w_s = expf(spec_logits[s] - sm) / ssum;
    float lp = lap_logits[s];
    float lap = (lp > 20.f) ? lp : log1pf(expf(lp));
    float le = lap * eigvals[s];

    __shared__ float red[4];
    float accR = 0.f, accL = 0.f;
    for (int k = 0; k < 4; ++k) {
        float phi = Phi[(k * NSPEC + s) * DIM + t];
        float v = phi * phi;
        for (int off = 32; off; off >>= 1) v += __shfl_xor(v, off);
        if ((t & 63) == 0) red[t >> 6] = v;
        __syncthreads();
        float ssq = red[0] + red[1] + red[2] + red[3];
        __syncthreads();
        float q = COEFF * phi / (1.f + COEFF * ssq);
        accR += hw[k] * q;
        accL += hw[k] * phi;
    }
    Tc[s * DIM + t] = spec_w_s * accR - le * accL;
    if (s == 0) {
        if (t < 4) out_tail[t] = hw[t];
        if (t < NSPEC) out_tail[4 + t] = expf(spec_logits[t] - sm) / ssum;
    }
}

// ---------------- final: G=V@Tc, H_half=H+ETA*G, soft-threshold, LayerNorm ----------------
__launch_bounds__(256)
__global__ void final_kernel(const float* __restrict__ H, const float* __restrict__ V,
                             const float* __restrict__ Tc, const float* __restrict__ thr,
                             const float* __restrict__ gamma, const float* __restrict__ beta,
                             float* __restrict__ out) {
    __shared__ float tc[NSPEC * DIM];   // 32 KB
    int t = threadIdx.x;
    {
        const float4* s4 = (const float4*)Tc;
        float4* d4 = (float4*)tc;
        for (int i = 0; i < 8; ++i) d4[i * 256 + t] = s4[i * 256 + t];
    }
    __syncthreads();
    int w = t >> 6, l = t & 63;
    long row = (long)blockIdx.x * 4 + w;
    int d0 = l * 4;
    const float* vrow = V + row * NSPEC;
    float4 G = {0.f, 0.f, 0.f, 0.f};
#pragma unroll 8
    for (int s = 0; s < NSPEC; ++s) {
        float vs = vrow[s];
        float4 c4 = *(const float4*)&tc[s * DIM + d0];
        G.x += vs * c4.x; G.y += vs * c4.y; G.z += vs * c4.z; G.w += vs * c4.w;
    }
    float4 h = *(const float4*)&H[row * DIM + d0];
    float4 th = *(const float4*)&thr[d0];
    float y[4];
    y[0] = h.x + ETA * G.x; y[1] = h.y + ETA * G.y;
    y[2] = h.z + ETA * G.z; y[3] = h.w + ETA * G.w;
    float tv[4] = {th.x, th.y, th.z, th.w};
    float s1 = 0.f, s2 = 0.f;
#pragma unroll
    for (int j = 0; j < 4; ++j) {
        float a = fabsf(y[j]) - tv[j];
        y[j] = (a > 0.f) ? copysignf(a, y[j]) : 0.f;
        s1 += y[j];
        s2 += y[j] * y[j];
    }
    for (int off = 32; off; off >>= 1) { s1 += __shfl_xor(s1, off); s2 += __shfl_xor(s2, off); }
    float mean = s1 * (1.f / DIM);
    float var = s2 * (1.f / DIM) - mean * mean;
    float inv = rsqrtf(var + LNEPS);
    float4 g4 = *(const float4*)&gamma[d0];
    float4 b4 = *(const float4*)&beta[d0];
    float4 o;
    o.x = (y[0] - mean) * inv * g4.x + b4.x;
    o.y = (y[1] - mean) * inv * g4.y + b4.y;
    o.z = (y[2] - mean) * inv * g4.z + b4.z;
    o.w = (y[3] - mean) * inv * g4.w + b4.w;
    *(float4*)&out[row * DIM + d0] = o;
}

extern "C" void kernel_launch(void* const* d_in, const int* in_sizes, int n_in,
                              void* d_out, int out_size, void* d_ws, size_t ws_size,
                              hipStream_t stream) {
    const float* H = (const float*)d_in[0];
    const float* A = (const float*)d_in[1];
    const float* V = (const float*)d_in[2];
    const float* eigvals = (const float*)d_in[3];
    const float* spec_logits = (const float*)d_in[4];
    const float* lap_logits = (const float*)d_in[5];
    const float* hop_weights = (const float*)d_in[6];
    const float* threshold = (const float*)d_in[7];
    const float* ln_gamma = (const float*)d_in[8];
    const float* ln_beta = (const float*)d_in[9];

    char* ws = (char*)d_ws;
    __hip_bfloat16* Abf  = (__hip_bfloat16*)ws;                      // 128 MB
    __hip_bfloat16* H0bf = (__hip_bfloat16*)(ws + 134217728);        // 4 MB m-major
    __hip_bfloat16* H0T  = (__hip_bfloat16*)(ws + 138412032);        // 4 MB d-major
    float*          P    = (float*)(ws + 142606336);                 // 32 MB split-K partials
    __hip_bfloat16* C1   = (__hip_bfloat16*)(ws + 176160768);
    __hip_bfloat16* C1T  = (__hip_bfloat16*)(ws + 180355072);
    __hip_bfloat16* C2   = (__hip_bfloat16*)(ws + 184549376);
    __hip_bfloat16* C2T  = (__hip_bfloat16*)(ws + 188743680);
    __hip_bfloat16* C3   = (__hip_bfloat16*)(ws + 192937984);
    float* Phi = (float*)(ws + 197132288);                           // 128 KB
    float* Tc  = (float*)(ws + 197263360);                           // 32 KB
    float* out = (float*)d_out;

    hipMemsetAsync(Phi, 0, 4 * NSPEC * DIM * sizeof(float), stream);
    cast_A<<<4096, 256, 0, stream>>>((const float4*)A, (ushort4*)Abf, NN * NN / 4);
    cast_trans<<<dim3(128, 4), 256, 0, stream>>>(H, H0bf, H0T);

    gemm_splitk<<<dim3(64, 2, KSPLIT), 256, 0, stream>>>(Abf, H0T, P);
    reduce_ct<<<dim3(128, 4), 256, 0, stream>>>(P, C1, C1T, 1);
    gemm_splitk<<<dim3(64, 2, KSPLIT), 256, 0, stream>>>(Abf, C1T, P);
    reduce_ct<<<dim3(128, 4), 256, 0, stream>>>(P, C2, C2T, 1);
    gemm_splitk<<<dim3(64, 2, KSPLIT), 256, 0, stream>>>(Abf, C2T, P);
    reduce_ct<<<dim3(128, 4), 256, 0, stream>>>(P, C3, C3, 0);

    phi_kernel<<<dim3(64, 4), 256, 0, stream>>>(V, H0bf, C1, C2, C3, Phi);
    tc_kernel<<<NSPEC, 256, 0, stream>>>(Phi, eigvals, spec_logits, lap_logits, hop_weights,
                                         Tc, out + (long)NN * DIM);
    final_kernel<<<2048, 256, 0, stream>>>(H, V, Tc, threshold, ln_gamma, ln_beta, out);
}

// Round 3
// 601.059 us; speedup vs baseline: 1.2711x; 1.1339x over previous
//
#include <hip/hip_runtime.h>
#include <hip/hip_bf16.h>
#include <stdint.h>

#define NN 8192
#define DIM 256
#define NSPEC 32
#define ETA 0.5f
#define COEFF 0.125f      // D/(N*EPS^2) = 256/(8192*0.25)
#define LNEPS 1e-5f

typedef __attribute__((ext_vector_type(8))) short bf16x8;
typedef __attribute__((ext_vector_type(4))) float f32x4;

__device__ __forceinline__ unsigned short bf2u(__hip_bfloat16 b) {
    union { __hip_bfloat16 b; unsigned short u; } c; c.b = b; return c.u;
}
__device__ __forceinline__ __hip_bfloat16 u2bf(unsigned short u) {
    union { __hip_bfloat16 b; unsigned short u; } c; c.u = u; return c.b;
}

__device__ __forceinline__ void async16(const void* g, void* l) {
    __builtin_amdgcn_global_load_lds(
        (const __attribute__((address_space(1))) void*)g,
        (__attribute__((address_space(3))) void*)l, 16, 0, 0);
}

// ---------------- cast + transpose A: f32 (8192x8192) -> bf16 ATbf[n,m] = A[m,n] -------------
__global__ void castT_A(const float* __restrict__ A, __hip_bfloat16* __restrict__ AT) {
    __shared__ unsigned short tile[64 * 66];
    int r0 = blockIdx.x * 64, c0 = blockIdx.y * 64;
    int t = threadIdx.x;
    for (int i = 0; i < 16; ++i) {
        int idx = i * 256 + t;
        int r = idx >> 6, c = idx & 63;
        tile[r * 66 + c] = bf2u(__float2bfloat16(A[(long)(r0 + r) * NN + c0 + c]));
    }
    __syncthreads();
    for (int i = 0; i < 16; ++i) {
        int idx = i * 256 + t;
        int c = idx >> 6, r = idx & 63;
        AT[(long)(c0 + c) * NN + r0 + r] = u2bf(tile[r * 66 + c]);
    }
}

// ---------------- transpose+cast V: f32 (8192x32) -> bf16 VT (32x8192) ----------------
__global__ void trans_V(const float* __restrict__ V, __hip_bfloat16* __restrict__ VT) {
    __shared__ float tile[64 * 33];
    int n0 = blockIdx.x * 64;
    int t = threadIdx.x;
    for (int i = 0; i < 8; ++i) {
        int idx = i * 256 + t;
        tile[(idx >> 5) * 33 + (idx & 31)] = V[(long)(n0 + (idx >> 5)) * NSPEC + (idx & 31)];
    }
    __syncthreads();
    for (int i = 0; i < 8; ++i) {
        int idx = i * 256 + t;
        int s = idx >> 6, r = idx & 63;
        VT[(long)s * NN + n0 + r] = __float2bfloat16(tile[r * 33 + s]);
    }
}

// ---------------- hop GEMM: W_next(8192x32 f32 partials) = ATbf(8192x8192) @ WT^T ------------
// A-operand rows from ATbf (m over k), B-operand rows from WT (32 x 8192, s over k).
// BM=128, BK=128, split-K=8 (Kc=1024, 8 iters). 256 thr = 4 waves (2m x 2n), wave-tile 64x16.
// Double-buffered LDS (2 x 40 KB = 80 KB), XOR-swizzled, global_load_lds width-16.
#define BM 128
#define BKH 128
#define HSPLIT 8
#define HKC (NN / HSPLIT)
#define HITERS (HKC / BKH)

__launch_bounds__(256, 2)
__global__ void gemm_hopW(const __hip_bfloat16* __restrict__ AT,
                          const __hip_bfloat16* __restrict__ WT,
                          float* __restrict__ P) {
    __shared__ __align__(16) __hip_bfloat16 As[2][BM * BKH];     // 2 x 32 KB
    __shared__ __align__(16) __hip_bfloat16 Ws[2][NSPEC * BKH];  // 2 x 8 KB
    const int t = threadIdx.x;
    const int w = t >> 6, l = t & 63;
    const int wm = w & 1, wn = w >> 1;
    const long gm0 = (long)blockIdx.x * BM;
    const long kbase = (long)blockIdx.y * HKC;

    const int lr4 = l >> 4;        // 0..3: row within one async16 wave-call (4 rows x 256 B)
    const int lg = l & 15;         // physical 16B group within row (16 groups)

    auto stage = [&](int buf, long kpos) {
#pragma unroll
        for (int c = 0; c < 8; ++c) {
            int rb = w * 32 + c * 4;
            int row = rb + lr4;
            async16(AT + (gm0 + row) * (long)NN + kpos + ((lg ^ (row & 15)) << 3),
                    &As[buf][rb * BKH]);
        }
#pragma unroll
        for (int c = 0; c < 2; ++c) {
            int rb = w * 8 + c * 4;
            int row = rb + lr4;
            async16(WT + (long)row * NN + kpos + ((lg ^ (row & 15)) << 3),
                    &Ws[buf][rb * BKH]);
        }
    };

    f32x4 acc[4];
#pragma unroll
    for (int mt = 0; mt < 4; ++mt) acc[mt] = (f32x4){0.f, 0.f, 0.f, 0.f};

    const int rowq = l & 15;
    const int kq = l >> 4;

    stage(0, kbase);
    for (int kt = 0; kt < HITERS; ++kt) {
        __syncthreads();                   // vmcnt drain: buf[cur] ready
        const int cur = kt & 1;
        if (kt + 1 < HITERS) stage(cur ^ 1, kbase + (long)(kt + 1) * BKH);

#pragma unroll
        for (int ks = 0; ks < 4; ++ks) {
            const int pg = ((ks * 4 + kq) ^ rowq) << 3;   // m&15 == n&15 == rowq
            bf16x8 bfrag = *(const bf16x8*)&Ws[cur][(wn * 16 + rowq) * BKH + pg];
#pragma unroll
            for (int mt = 0; mt < 4; ++mt) {
                bf16x8 afrag = *(const bf16x8*)&As[cur][(wm * 64 + mt * 16 + rowq) * BKH + pg];
                acc[mt] = __builtin_amdgcn_mfma_f32_16x16x32_bf16(afrag, bfrag, acc[mt], 0, 0, 0);
            }
        }
    }

    // C/D layout: col = lane&15, row = (lane>>4)*4 + reg
    float* Pz = P + (long)blockIdx.y * NN * NSPEC;
    const int s = wn * 16 + (l & 15);
#pragma unroll
    for (int mt = 0; mt < 4; ++mt)
#pragma unroll
        for (int r = 0; r < 4; ++r) {
            long m = gm0 + wm * 64 + mt * 16 + (l >> 4) * 4 + r;
            Pz[m * NSPEC + s] = acc[mt][r];
        }
}

// ---------------- reduce split-K partials -> W f32 (8192x32) + WT bf16 (32x8192) -------------
__global__ void reduce_W(const float* __restrict__ P, float* __restrict__ Wf,
                         __hip_bfloat16* __restrict__ WTbf) {
    __shared__ float tile[64 * 33];
    int n0 = blockIdx.x * 64;
    int t = threadIdx.x;
    for (int i = 0; i < 8; ++i) {
        int idx = i * 256 + t;
        int r = idx >> 5, s = idx & 31;
        long off = (long)(n0 + r) * NSPEC + s;
        float v = 0.f;
#pragma unroll
        for (int z = 0; z < HSPLIT; ++z) v += P[(long)z * NN * NSPEC + off];
        Wf[off] = v;
        tile[r * 33 + s] = v;
    }
    __syncthreads();
    for (int i = 0; i < 8; ++i) {
        int idx = i * 256 + t;
        int s = idx >> 6, r = idx & 63;
        WTbf[(long)s * NN + n0 + r] = __float2bfloat16(tile[r * 33 + s]);
    }
}

// ---------------- Phi[k,s,d] = sum_n W_k[n,s] * H[n,d]  (f32, atomic split over n) -----------
__global__ void phi_kernel(const float* __restrict__ W0, const float* __restrict__ W1,
                           const float* __restrict__ W2, const float* __restrict__ W3,
                           const float* __restrict__ H, float* __restrict__ Phi) {
    __shared__ float ldsW[64 * NSPEC];   // 8 KB
    int t = threadIdx.x;
    int s0 = (t >> 6) * 8;
    int d0 = (t & 63) * 4;
    int n0 = blockIdx.x * 128;
    int k = blockIdx.y;
    const float* W = (k == 0) ? W0 : (k == 1) ? W1 : (k == 2) ? W2 : W3;
    float4 acc[8];
#pragma unroll
    for (int j = 0; j < 8; ++j) acc[j] = (float4){0.f, 0.f, 0.f, 0.f};

    for (int tile = 0; tile < 2; ++tile) {
        int nb = n0 + tile * 64;
#pragma unroll
        for (int i = 0; i < 8; ++i) {
            int idx = i * 256 + t;
            ldsW[idx] = W[(long)(nb + (idx >> 5)) * NSPEC + (idx & 31)];
        }
        __syncthreads();
        for (int nn = 0; nn < 64; ++nn) {
            float4 x = *(const float4*)&H[(long)(nb + nn) * DIM + d0];
#pragma unroll
            for (int j = 0; j < 8; ++j) {
                float vs = ldsW[nn * NSPEC + s0 + j];
                acc[j].x += vs * x.x; acc[j].y += vs * x.y;
                acc[j].z += vs * x.z; acc[j].w += vs * x.w;
            }
        }
        __syncthreads();
    }
#pragma unroll
    for (int j = 0; j < 8; ++j) {
        float* ph = &Phi[((k * NSPEC) + s0 + j) * DIM + d0];
        atomicAdd(ph + 0, acc[j].x);
        atomicAdd(ph + 1, acc[j].y);
        atomicAdd(ph + 2, acc[j].z);
        atomicAdd(ph + 3, acc[j].w);
    }
}

// ---------------- Tc[s,d] = spec_w*sum_k hw*q - lap*eig*sum_k hw*phi; + tail outputs ---------
__global__ void tc_kernel(const float* __restrict__ Phi,
                          const float* __restrict__ eigvals,
                          const float* __restrict__ spec_logits,
                          const float* __restrict__ lap_logits,
                          const float* __restrict__ hop_weights,
                          float* __restrict__ Tc,
                          float* __restrict__ out_tail) {
    int s = blockIdx.x, t = threadIdx.x;
    float hw0 = hop_weights[0], hw1 = hop_weights[1], hw2 = hop_weights[2], hw3 = hop_weights[3];
    float hm = fmaxf(fmaxf(hw0, hw1), fmaxf(hw2, hw3));
    hw0 = expf(hw0 - hm); hw1 = expf(hw1 - hm); hw2 = expf(hw2 - hm); hw3 = expf(hw3 - hm);
    float hs = hw0 + hw1 + hw2 + hw3;
    hw0 /= hs; hw1 /= hs; hw2 /= hs; hw3 /= hs;
    float hw[4] = {hw0, hw1, hw2, hw3};
    float sm = -1e30f;
    for (int j = 0; j < NSPEC; ++j) sm = fmaxf(sm, spec_logits[j]);
    float ssum = 0.f;
    for (int j = 0; j < NSPEC; ++j) ssum += expf(spec_logits[j] - sm);
    float spec_w_s = expf(spec_logits[s] - sm) / ssum;
    float lp = lap_logits[s];
    float lap = (lp > 20.f) ? lp : log1pf(expf(lp));
    float le = lap * eigvals[s];

    __shared__ float red[4];
    float accR = 0.f, accL = 0.f;
    for (int k = 0; k < 4; ++k) {
        float phi = Phi[(k * NSPEC + s) * DIM + t];
        float v = phi * phi;
        for (int off = 32; off; off >>= 1) v += __shfl_xor(v, off);
        if ((t & 63) == 0) red[t >> 6] = v;
        __syncthreads();
        float ssq = red[0] + red[1] + red[2] + red[3];
        __syncthreads();
        float q = COEFF * phi / (1.f + COEFF * ssq);   // Sherman-Morrison: solve(I+c*pp^T, p)
        accR += hw[k] * q;
        accL += hw[k] * phi;
    }
    Tc[s * DIM + t] = spec_w_s * accR - le * accL;
    if (s == 0) {
        if (t < 4) out_tail[t] = hw[t];
        if (t < NSPEC) out_tail[4 + t] = expf(spec_logits[t] - sm) / ssum;
    }
}

// ---------------- final: G=V@Tc, H_half=H+ETA*G, soft-threshold, LayerNorm ----------------
__launch_bounds__(256)
__global__ void final_kernel(const float* __restrict__ H, const float* __restrict__ V,
                             const float* __restrict__ Tc, const float* __restrict__ thr,
                             const float* __restrict__ gamma, const float* __restrict__ beta,
                             float* __restrict__ out) {
    __shared__ float tc[NSPEC * DIM];   // 32 KB
    int t = threadIdx.x;
    {
        const float4* s4 = (const float4*)Tc;
        float4* d4 = (float4*)tc;
        for (int i = 0; i < 8; ++i) d4[i * 256 + t] = s4[i * 256 + t];
    }
    __syncthreads();
    int w = t >> 6, l = t & 63;
    long row = (long)blockIdx.x * 4 + w;
    int d0 = l * 4;
    const float* vrow = V + row * NSPEC;
    float4 G = {0.f, 0.f, 0.f, 0.f};
#pragma unroll 8
    for (int s = 0; s < NSPEC; ++s) {
        float vs = vrow[s];
        float4 c4 = *(const float4*)&tc[s * DIM + d0];
        G.x += vs * c4.x; G.y += vs * c4.y; G.z += vs * c4.z; G.w += vs * c4.w;
    }
    float4 h = *(const float4*)&H[row * DIM + d0];
    float4 th = *(const float4*)&thr[d0];
    float y[4];
    y[0] = h.x + ETA * G.x; y[1] = h.y + ETA * G.y;
    y[2] = h.z + ETA * G.z; y[3] = h.w + ETA * G.w;
    float tv[4] = {th.x, th.y, th.z, th.w};
    float s1 = 0.f, s2 = 0.f;
#pragma unroll
    for (int j = 0; j < 4; ++j) {
        float a = fabsf(y[j]) - tv[j];
        y[j] = (a > 0.f) ? copysignf(a, y[j]) : 0.f;
        s1 += y[j];
        s2 += y[j] * y[j];
    }
    for (int off = 32; off; off >>= 1) { s1 += __shfl_xor(s1, off); s2 += __shfl_xor(s2, off); }
    float mean = s1 * (1.f / DIM);
    float var = s2 * (1.f / DIM) - mean * mean;
    float inv = rsqrtf(var + LNEPS);
    float4 g4 = *(const float4*)&gamma[d0];
    float4 b4 = *(const float4*)&beta[d0];
    float4 o;
    o.x = (y[0] - mean) * inv * g4.x + b4.x;
    o.y = (y[1] - mean) * inv * g4.y + b4.y;
    o.z = (y[2] - mean) * inv * g4.z + b4.z;
    o.w = (y[3] - mean) * inv * g4.w + b4.w;
    *(float4*)&out[row * DIM + d0] = o;
}

extern "C" void kernel_launch(void* const* d_in, const int* in_sizes, int n_in,
                              void* d_out, int out_size, void* d_ws, size_t ws_size,
                              hipStream_t stream) {
    const float* H = (const float*)d_in[0];
    const float* A = (const float*)d_in[1];
    const float* V = (const float*)d_in[2];
    const float* eigvals = (const float*)d_in[3];
    const float* spec_logits = (const float*)d_in[4];
    const float* lap_logits = (const float*)d_in[5];
    const float* hop_weights = (const float*)d_in[6];
    const float* threshold = (const float*)d_in[7];
    const float* ln_gamma = (const float*)d_in[8];
    const float* ln_beta = (const float*)d_in[9];

    char* ws = (char*)d_ws;
    __hip_bfloat16* ATbf = (__hip_bfloat16*)ws;                      // 128 MB
    float*          P    = (float*)(ws + 134217728);                 // 8 MB split-K partials
    __hip_bfloat16* VTbf = (__hip_bfloat16*)(ws + 142606336);        // 0.5 MB
    float* W1f = (float*)(ws + 143130624);                           // 1 MB
    float* W2f = (float*)(ws + 144179200);                           // 1 MB
    float* W3f = (float*)(ws + 145227776);                           // 1 MB
    __hip_bfloat16* W1T = (__hip_bfloat16*)(ws + 146276352);         // 0.5 MB
    __hip_bfloat16* W2T = (__hip_bfloat16*)(ws + 146800640);         // 0.5 MB
    __hip_bfloat16* W3T = (__hip_bfloat16*)(ws + 147324928);         // 0.5 MB (unused output)
    float* Phi = (float*)(ws + 147849216);                           // 128 KB
    float* Tc  = (float*)(ws + 147980288);                           // 32 KB
    float* out = (float*)d_out;

    hipMemsetAsync(Phi, 0, 4 * NSPEC * DIM * sizeof(float), stream);
    castT_A<<<dim3(128, 128), 256, 0, stream>>>(A, ATbf);
    trans_V<<<128, 256, 0, stream>>>(V, VTbf);

    gemm_hopW<<<dim3(64, HSPLIT), 256, 0, stream>>>(ATbf, VTbf, P);
    reduce_W<<<128, 256, 0, stream>>>(P, W1f, W1T);
    gemm_hopW<<<dim3(64, HSPLIT), 256, 0, stream>>>(ATbf, W1T, P);
    reduce_W<<<128, 256, 0, stream>>>(P, W2f, W2T);
    gemm_hopW<<<dim3(64, HSPLIT), 256, 0, stream>>>(ATbf, W2T, P);
    reduce_W<<<128, 256, 0, stream>>>(P, W3f, W3T);

    phi_kernel<<<dim3(64, 4), 256, 0, stream>>>(V, W1f, W2f, W3f, H, Phi);
    tc_kernel<<<NSPEC, 256, 0, stream>>>(Phi, eigvals, spec_logits, lap_logits, hop_weights,
                                         Tc, out + (long)NN * DIM);
    final_kernel<<<2048, 256, 0, stream>>>(H, V, Tc, threshold, ln_gamma, ln_beta, out);
}